// Round 1
// baseline (10793.771 us; speedup 1.0000x reference)
//
#include <hip/hip_runtime.h>

typedef unsigned short ushort_t;
typedef __attribute__((ext_vector_type(8))) short short8;
typedef __attribute__((ext_vector_type(4))) float floatx4;

#define S_LEN 1024
#define BATCH 32
#define HDIM  256
#define GDIM  1024  /* 4H */
#define DIN   128

__device__ __forceinline__ float bf2f(ushort_t u) { return __uint_as_float(((unsigned)u) << 16); }
__device__ __forceinline__ float bf2fs(short s)   { return __uint_as_float(((unsigned)(unsigned short)s) << 16); }
__device__ __forceinline__ ushort_t f2bf(float f) {
  unsigned u = __float_as_uint(f);
  unsigned r = (u + 0x7fffu + ((u >> 16) & 1u)) >> 16;
  return (ushort_t)r;
}
__device__ __forceinline__ float sigf(float x) { return 1.f / (1.f + __expf(-x)); }
__device__ __forceinline__ float tanh_f(float x) {
  float ax = fabsf(x);
  float e = __expf(2.f * ax);
  float r = 1.f - 2.f / (e + 1.f);
  return x < 0.f ? -r : r;
}

__device__ __forceinline__ void load_lds16(const void* g, void* l) {
  __builtin_amdgcn_global_load_lds((const __attribute__((address_space(1))) unsigned int*)g,
                                   (__attribute__((address_space(3))) unsigned int*)l, 16, 0, 0);
}

// ---------------------------------------------------------------------------
// Generic bf16 MFMA GEMM: C[m][n] = sum_k A[m][k]*B[n][k] + bias[n]
// A: (M,K) bf16 row-major, B: (N,K) bf16 row-major ("B^T input" form).
// mode 0: store bf16 at C[m*N+n].   mode 1 (head): store fp32 at
//         out[b*S*128 + t*128 + n] with m = t*32+b.
// Block 256 thr = 4 waves (2x2), 128x128 tile, BK=64, XOR-swizzled LDS,
// global_load_lds width-16 staging.
// ---------------------------------------------------------------------------
__global__ __launch_bounds__(256) void gemm_bf16(
    const ushort_t* __restrict__ A, const ushort_t* __restrict__ Bw,
    const float* __restrict__ bias, void* __restrict__ Cout,
    int M, int N, int K, int mode)
{
  __shared__ __align__(16) ushort_t As[128 * 64];
  __shared__ __align__(16) ushort_t Bs[128 * 64];
  const int tid = threadIdx.x;
  const int lane = tid & 63, wid = tid >> 6;
  const int wm = wid >> 1, wn = wid & 1;
  const int bm = blockIdx.y, bn = blockIdx.x;
  const int l15 = lane & 15, q4 = lane >> 4;

  const int r  = tid >> 3;       // staging row within 32-row pass
  const int c8 = tid & 7;        // LDS slot
  const int g8 = c8 ^ (r & 7);   // swizzled global col-group

  floatx4 zero4 = {0.f, 0.f, 0.f, 0.f};
  floatx4 acc[4][4];
#pragma unroll
  for (int mt = 0; mt < 4; ++mt)
#pragma unroll
    for (int nt = 0; nt < 4; ++nt) acc[mt][nt] = zero4;

  for (int k0 = 0; k0 < K; k0 += 64) {
    __syncthreads();
#pragma unroll
    for (int p = 0; p < 4; ++p) {
      int row = p * 32 + r;
      load_lds16(A + (size_t)(bm * 128 + row) * K + k0 + g8 * 8, (void*)(As + p * 2048 + wid * 512));
      load_lds16(Bw + (size_t)(bn * 128 + row) * K + k0 + g8 * 8, (void*)(Bs + p * 2048 + wid * 512));
    }
    __syncthreads();
#pragma unroll
    for (int ks = 0; ks < 2; ++ks) {
      const int kk = ks * 4 + q4;
      short8 af[4], bf[4];
#pragma unroll
      for (int mt = 0; mt < 4; ++mt) {
        int row = wm * 64 + mt * 16 + l15;
        af[mt] = *(const short8*)(As + row * 64 + ((kk ^ (row & 7)) << 3));
      }
#pragma unroll
      for (int nt = 0; nt < 4; ++nt) {
        int row = wn * 64 + nt * 16 + l15;
        bf[nt] = *(const short8*)(Bs + row * 64 + ((kk ^ (row & 7)) << 3));
      }
#pragma unroll
      for (int mt = 0; mt < 4; ++mt)
#pragma unroll
        for (int nt = 0; nt < 4; ++nt)
          acc[mt][nt] = __builtin_amdgcn_mfma_f32_16x16x32_bf16(af[mt], bf[nt], acc[mt][nt], 0, 0, 0);
    }
  }

#pragma unroll
  for (int mt = 0; mt < 4; ++mt)
#pragma unroll
    for (int nt = 0; nt < 4; ++nt)
#pragma unroll
      for (int rr = 0; rr < 4; ++rr) {
        int m = bm * 128 + wm * 64 + mt * 16 + q4 * 4 + rr;
        int n = bn * 128 + wn * 64 + nt * 16 + l15;
        float v = acc[mt][nt][rr] + bias[n];
        if (mode == 0) {
          ((ushort_t*)Cout)[(size_t)m * N + n] = f2bf(v);
        } else {
          int t = m >> 5, b = m & 31;
          ((float*)Cout)[(size_t)b * (S_LEN * DIN) + t * DIN + n] = v;
        }
      }
}

// ---------------------------------------------------------------------------
// One bidirectional LSTM layer recurrence. Grid 64 blocks: d = blockIdx%8
// (0=fwd, 1=bwd, others idle), j = blockIdx/8 = slice 0..7 (32 h-cols each).
// Each WG holds its 128 w_hh rows ([i|f|g|o] blocks of 32, wave w = block w)
// as register B-fragments; per step does 32x128 gates via MFMA, elementwise
// in fp32, publishes its h-slice, and syncs the 8-WG group via an agent-scope
// atomic counter.
// ---------------------------------------------------------------------------
__global__ __launch_bounds__(256) void lstm_layer(
    const ushort_t* __restrict__ xpf, const ushort_t* __restrict__ xpb,
    const ushort_t* __restrict__ whhf, const ushort_t* __restrict__ whhb,
    ushort_t* __restrict__ hout, ushort_t* __restrict__ comm, unsigned* __restrict__ cnt)
{
  const int bx = blockIdx.x;
  const int d = bx & 7, j = bx >> 3;
  if (d >= 2) return;

  const ushort_t* xp  = d ? xpb : xpf;
  const ushort_t* whh = d ? whhb : whhf;
  ushort_t* commd = comm + d * 16384;  // 2 ping-pong bufs x 32*256
  unsigned* cn = cnt + d * 64;
  const int hoff = d * 256;

  __shared__ __align__(16) float stage[32 * 132];

  const int tid = threadIdx.x, lane = tid & 63, w = tid >> 6;
  const int l15 = lane & 15, q4 = lane >> 4;

  // permanent B-fragments: wave w owns gate block w of this slice
  short8 Bf[2][8];
#pragma unroll
  for (int tl = 0; tl < 2; ++tl) {
    int grow = w * 256 + j * 32 + tl * 16 + l15;
#pragma unroll
    for (int ks = 0; ks < 8; ++ks)
      Bf[tl][ks] = *(const short8*)(whh + (size_t)grow * 256 + ks * 32 + q4 * 8);
  }

  float cst[4] = {0.f, 0.f, 0.f, 0.f};

  ushort_t xr[2][2][4];
  auto ldxp = [&](int tt) {
#pragma unroll
    for (int mt = 0; mt < 2; ++mt)
#pragma unroll
      for (int tl = 0; tl < 2; ++tl) {
        int g = w * 256 + j * 32 + tl * 16 + l15;
#pragma unroll
        for (int rr = 0; rr < 4; ++rr) {
          int b = mt * 16 + q4 * 4 + rr;
          xr[mt][tl][rr] = xp[(size_t)tt * (BATCH * GDIM) + b * GDIM + g];
        }
      }
  };

  int t0 = (d == 0) ? 0 : 1023;
  ldxp(t0);

  for (int sc = 0; sc < 1024; ++sc) {
    const int tcur  = (d == 0) ? sc : 1023 - sc;
    const int tnext = (d == 0) ? (sc < 1023 ? sc + 1 : 1023) : (sc < 1023 ? 1022 - sc : 0);

    floatx4 acc[2][2];
#pragma unroll
    for (int mt = 0; mt < 2; ++mt)
#pragma unroll
      for (int tl = 0; tl < 2; ++tl)
#pragma unroll
        for (int rr = 0; rr < 4; ++rr) acc[mt][tl][rr] = bf2f(xr[mt][tl][rr]);

    ldxp(tnext);  // prefetch next step's xp (latency hidden behind MFMA+barrier)

    const ushort_t* cp = commd + ((sc & 1) ^ 1) * 8192;  // h_{t-1}
    ushort_t* cw = commd + (sc & 1) * 8192;              // h_t

#pragma unroll
    for (int ks = 0; ks < 8; ++ks) {
      short8 a0 = *(const short8*)(cp + (size_t)l15 * 256 + ks * 32 + q4 * 8);
      short8 a1 = *(const short8*)(cp + (size_t)(16 + l15) * 256 + ks * 32 + q4 * 8);
      acc[0][0] = __builtin_amdgcn_mfma_f32_16x16x32_bf16(a0, Bf[0][ks], acc[0][0], 0, 0, 0);
      acc[0][1] = __builtin_amdgcn_mfma_f32_16x16x32_bf16(a0, Bf[1][ks], acc[0][1], 0, 0, 0);
      acc[1][0] = __builtin_amdgcn_mfma_f32_16x16x32_bf16(a1, Bf[0][ks], acc[1][0], 0, 0, 0);
      acc[1][1] = __builtin_amdgcn_mfma_f32_16x16x32_bf16(a1, Bf[1][ks], acc[1][1], 0, 0, 0);
    }

#pragma unroll
    for (int mt = 0; mt < 2; ++mt)
#pragma unroll
      for (int tl = 0; tl < 2; ++tl)
#pragma unroll
        for (int rr = 0; rr < 4; ++rr)
          stage[(mt * 16 + q4 * 4 + rr) * 132 + w * 32 + tl * 16 + l15] = acc[mt][tl][rr];
    __syncthreads();

#pragma unroll
    for (int rr = 0; rr < 4; ++rr) {
      int e = tid + rr * 256;
      int b = e >> 5, q = e & 31;
      float gi = stage[b * 132 + q];
      float gf = stage[b * 132 + 32 + q];
      float gg = stage[b * 132 + 64 + q];
      float go = stage[b * 132 + 96 + q];
      float c = sigf(gf) * cst[rr] + sigf(gi) * tanh_f(gg);
      cst[rr] = c;
      float h = sigf(go) * tanh_f(c);
      ushort_t hb = f2bf(h);
      cw[b * 256 + j * 32 + q] = hb;
      hout[(size_t)tcur * (BATCH * 512) + b * 512 + hoff + j * 32 + q] = hb;
    }
    __syncthreads();

    if (tid == 0) {
      __hip_atomic_fetch_add(cn, 1u, __ATOMIC_RELEASE, __HIP_MEMORY_SCOPE_AGENT);
      unsigned tgt = 8u * (unsigned)(sc + 1);
      while (__hip_atomic_load(cn, __ATOMIC_RELAXED, __HIP_MEMORY_SCOPE_AGENT) < tgt)
        __builtin_amdgcn_s_sleep(2);
      __builtin_amdgcn_fence(__ATOMIC_ACQUIRE, "agent");
    }
    __syncthreads();
  }
}

// ---------------------------------------------------------------------------
// Attention scores -> e = exp(s - max_t s), per batch b.
// ---------------------------------------------------------------------------
__global__ __launch_bounds__(256) void attn_scores(
    const ushort_t* __restrict__ h1, const float* __restrict__ attn_w,
    const float* __restrict__ attn_b, float* __restrict__ e_out)
{
  const int b = blockIdx.x;
  __shared__ float sbuf[1024];
  __shared__ float red[4];
  const int tid = threadIdx.x, lane = tid & 63, w = tid >> 6;

  float wreg[8];
#pragma unroll
  for (int i = 0; i < 8; ++i) wreg[i] = attn_w[lane * 8 + i];

  for (int t = w; t < 1024; t += 4) {
    short8 hv = *(const short8*)(h1 + (size_t)t * (BATCH * 512) + b * 512 + lane * 8);
    float dot = 0.f;
#pragma unroll
    for (int i = 0; i < 8; ++i) dot += bf2fs(hv[i]) * wreg[i];
#pragma unroll
    for (int off = 32; off; off >>= 1) dot += __shfl_xor(dot, off);
    if (lane == 0) sbuf[t] = dot + attn_b[0];
  }
  __syncthreads();
  float m = -1e30f;
  for (int t = tid; t < 1024; t += 256) m = fmaxf(m, sbuf[t]);
#pragma unroll
  for (int off = 32; off; off >>= 1) m = fmaxf(m, __shfl_xor(m, off));
  if (lane == 0) red[w] = m;
  __syncthreads();
  float mm = fmaxf(fmaxf(red[0], red[1]), fmaxf(red[2], red[3]));
  for (int t = tid; t < 1024; t += 256) e_out[b * 1024 + t] = __expf(sbuf[t] - mm);
}

// ---------------------------------------------------------------------------
// Cumulative context: ctx[t][b][c] = (sum_{u<=t} e_u h_u[c]) / (sum e_u), bf16.
// ---------------------------------------------------------------------------
__global__ __launch_bounds__(256) void attn_ctx(
    const ushort_t* __restrict__ h1, const float* __restrict__ e_in, ushort_t* __restrict__ ctx)
{
  const int b = blockIdx.x >> 1, half = blockIdx.x & 1;
  const int c = half * 256 + threadIdx.x;
  float num = 0.f, den = 0.f;
  const ushort_t* hp = h1 + b * 512 + c;
  ushort_t* cp = ctx + b * 512 + c;
  const float* ep = e_in + b * 1024;
#pragma unroll 4
  for (int t = 0; t < 1024; ++t) {
    float ev = ep[t];
    float hv = bf2f(hp[(size_t)t * (BATCH * 512)]);
    num += ev * hv;
    den += ev;
    cp[(size_t)t * (BATCH * 512)] = f2bf(num / den);
  }
}

// ---------------------------------------------------------------------------
// casts
// ---------------------------------------------------------------------------
__global__ void castw(const float* __restrict__ in, ushort_t* __restrict__ out, int n) {
  int i = blockIdx.x * 256 + threadIdx.x;
  if (i < n) out[i] = f2bf(in[i]);
}
__global__ void castx(const float* __restrict__ x, ushort_t* __restrict__ xt) {
  int i = blockIdx.x * 256 + threadIdx.x;  // over 32768*128
  int dcol = i & 127;
  int m = i >> 7;
  int b = m & 31, s = m >> 5;
  xt[i] = f2bf(x[(size_t)b * (S_LEN * DIN) + s * DIN + dcol]);
}

extern "C" void kernel_launch(void* const* d_in, const int* in_sizes, int n_in,
                              void* d_out, int out_size, void* d_ws, size_t ws_size,
                              hipStream_t stream)
{
  const float* x     = (const float*)d_in[0];
  const float* wih0f = (const float*)d_in[1];
  const float* whh0f = (const float*)d_in[2];
  const float* b0f   = (const float*)d_in[3];
  const float* wih0b = (const float*)d_in[4];
  const float* whh0b = (const float*)d_in[5];
  const float* b0b   = (const float*)d_in[6];
  const float* wih1f = (const float*)d_in[7];
  const float* whh1f = (const float*)d_in[8];
  const float* b1f   = (const float*)d_in[9];
  const float* wih1b = (const float*)d_in[10];
  const float* whh1b = (const float*)d_in[11];
  const float* b1b   = (const float*)d_in[12];
  const float* attw  = (const float*)d_in[13];
  const float* attb  = (const float*)d_in[14];
  const float* headw = (const float*)d_in[15];
  const float* headb = (const float*)d_in[16];
  float* out = (float*)d_out;

  char* p = (char*)d_ws;
  auto alloc = [&](size_t bytes) {
    char* r = p;
    p += (bytes + 255) & ~(size_t)255;
    return r;
  };
  unsigned* cnt   = (unsigned*)alloc(1024);
  ushort_t* comm  = (ushort_t*)alloc(65536);
  ushort_t* xt    = (ushort_t*)alloc((size_t)32768 * 128 * 2);
  ushort_t* cwih0f = (ushort_t*)alloc(131072 * 2);
  ushort_t* cwih0b = (ushort_t*)alloc(131072 * 2);
  ushort_t* cwhh0f = (ushort_t*)alloc(262144 * 2);
  ushort_t* cwhh0b = (ushort_t*)alloc(262144 * 2);
  ushort_t* cwih1f = (ushort_t*)alloc(524288 * 2);
  ushort_t* cwih1b = (ushort_t*)alloc(524288 * 2);
  ushort_t* cwhh1f = (ushort_t*)alloc(262144 * 2);
  ushort_t* cwhh1b = (ushort_t*)alloc(262144 * 2);
  ushort_t* cwhead = (ushort_t*)alloc(65536 * 2);
  ushort_t* xpA = (ushort_t*)alloc((size_t)32768 * 1024 * 2);
  ushort_t* xpB = (ushort_t*)alloc((size_t)32768 * 1024 * 2);
  ushort_t* h0  = (ushort_t*)alloc((size_t)32768 * 512 * 2);
  ushort_t* h1  = (ushort_t*)alloc((size_t)32768 * 512 * 2);
  float* ebuf   = (float*)alloc(32 * 1024 * 4);
  ushort_t* ctx = xpA;  // reuse (xp dead by then)

  (void)in_sizes; (void)n_in; (void)out_size; (void)ws_size;

  // zero barrier counters + h comm (h_{-1} = 0) for layer 0
  (void)hipMemsetAsync(cnt, 0, 1024 + 65536, stream);

  castw<<<512, 256, 0, stream>>>(wih0f, cwih0f, 131072);
  castw<<<512, 256, 0, stream>>>(wih0b, cwih0b, 131072);
  castw<<<1024, 256, 0, stream>>>(whh0f, cwhh0f, 262144);
  castw<<<1024, 256, 0, stream>>>(whh0b, cwhh0b, 262144);
  castw<<<2048, 256, 0, stream>>>(wih1f, cwih1f, 524288);
  castw<<<2048, 256, 0, stream>>>(wih1b, cwih1b, 524288);
  castw<<<1024, 256, 0, stream>>>(whh1f, cwhh1f, 262144);
  castw<<<1024, 256, 0, stream>>>(whh1b, cwhh1b, 262144);
  castw<<<256, 256, 0, stream>>>(headw, cwhead, 65536);
  castx<<<16384, 256, 0, stream>>>(x, xt);

  // layer 0 input projections
  gemm_bf16<<<dim3(8, 256), 256, 0, stream>>>(xt, cwih0f, b0f, xpA, 32768, 1024, 128, 0);
  gemm_bf16<<<dim3(8, 256), 256, 0, stream>>>(xt, cwih0b, b0b, xpB, 32768, 1024, 128, 0);
  // layer 0 recurrence
  lstm_layer<<<64, 256, 0, stream>>>(xpA, xpB, cwhh0f, cwhh0b, h0, comm, cnt);

  // reset barrier + comm for layer 1
  (void)hipMemsetAsync(cnt, 0, 1024 + 65536, stream);

  // layer 1 input projections (reuse xp buffers)
  gemm_bf16<<<dim3(8, 256), 256, 0, stream>>>(h0, cwih1f, b1f, xpA, 32768, 1024, 512, 0);
  gemm_bf16<<<dim3(8, 256), 256, 0, stream>>>(h0, cwih1b, b1b, xpB, 32768, 1024, 512, 0);
  // layer 1 recurrence
  lstm_layer<<<64, 256, 0, stream>>>(xpA, xpB, cwhh1f, cwhh1b, h1, comm, cnt);

  // attention + head
  attn_scores<<<32, 256, 0, stream>>>(h1, attw, attb, ebuf);
  attn_ctx<<<64, 256, 0, stream>>>(h1, ebuf, ctx);
  gemm_bf16<<<dim3(1, 256), 256, 0, stream>>>(ctx, cwhead, headb, out, 32768, 128, 512, 1);
}

// Round 3
// 10194.091 us; speedup vs baseline: 1.0588x; 1.0588x over previous
//
#include <hip/hip_runtime.h>

typedef unsigned short ushort_t;
typedef unsigned int uint_t;
typedef unsigned long long u64;
typedef __attribute__((ext_vector_type(8))) short short8;
typedef __attribute__((ext_vector_type(4))) float floatx4;

#define S_LEN 1024
#define BATCH 32
#define HDIM  256
#define GDIM  1024  /* 4H */
#define DIN   128

__device__ __forceinline__ float bf2f(ushort_t u) { return __uint_as_float(((unsigned)u) << 16); }
__device__ __forceinline__ float bf2fs(short s)   { return __uint_as_float(((unsigned)(unsigned short)s) << 16); }
__device__ __forceinline__ ushort_t f2bf(float f) {
  unsigned u = __float_as_uint(f);
  unsigned r = (u + 0x7fffu + ((u >> 16) & 1u)) >> 16;
  return (ushort_t)r;
}
__device__ __forceinline__ float sigf(float x) { return 1.f / (1.f + __expf(-x)); }
__device__ __forceinline__ float tanh_f(float x) {
  float ax = fabsf(x);
  float e = __expf(2.f * ax);
  float r = 1.f - 2.f / (e + 1.f);
  return x < 0.f ? -r : r;
}

__device__ __forceinline__ void load_lds16(const void* g, void* l) {
  __builtin_amdgcn_global_load_lds((const __attribute__((address_space(1))) unsigned int*)g,
                                   (__attribute__((address_space(3))) unsigned int*)l, 16, 0, 0);
}

// ---------------------------------------------------------------------------
// Generic bf16 MFMA GEMM: C[m][n] = sum_k A[m][k]*B[n][k] + bias[n]
// ---------------------------------------------------------------------------
__global__ __launch_bounds__(256) void gemm_bf16(
    const ushort_t* __restrict__ A, const ushort_t* __restrict__ Bw,
    const float* __restrict__ bias, void* __restrict__ Cout,
    int M, int N, int K, int mode)
{
  __shared__ __align__(16) ushort_t As[128 * 64];
  __shared__ __align__(16) ushort_t Bs[128 * 64];
  const int tid = threadIdx.x;
  const int lane = tid & 63, wid = tid >> 6;
  const int wm = wid >> 1, wn = wid & 1;
  const int bm = blockIdx.y, bn = blockIdx.x;
  const int l15 = lane & 15, q4 = lane >> 4;

  const int r  = tid >> 3;
  const int c8 = tid & 7;
  const int g8 = c8 ^ (r & 7);

  floatx4 zero4 = {0.f, 0.f, 0.f, 0.f};
  floatx4 acc[4][4];
#pragma unroll
  for (int mt = 0; mt < 4; ++mt)
#pragma unroll
    for (int nt = 0; nt < 4; ++nt) acc[mt][nt] = zero4;

  for (int k0 = 0; k0 < K; k0 += 64) {
    __syncthreads();
#pragma unroll
    for (int p = 0; p < 4; ++p) {
      int row = p * 32 + r;
      load_lds16(A + (size_t)(bm * 128 + row) * K + k0 + g8 * 8, (void*)(As + p * 2048 + wid * 512));
      load_lds16(Bw + (size_t)(bn * 128 + row) * K + k0 + g8 * 8, (void*)(Bs + p * 2048 + wid * 512));
    }
    __syncthreads();
#pragma unroll
    for (int ks = 0; ks < 2; ++ks) {
      const int kk = ks * 4 + q4;
      short8 af[4], bf[4];
#pragma unroll
      for (int mt = 0; mt < 4; ++mt) {
        int row = wm * 64 + mt * 16 + l15;
        af[mt] = *(const short8*)(As + row * 64 + ((kk ^ (row & 7)) << 3));
      }
#pragma unroll
      for (int nt = 0; nt < 4; ++nt) {
        int row = wn * 64 + nt * 16 + l15;
        bf[nt] = *(const short8*)(Bs + row * 64 + ((kk ^ (row & 7)) << 3));
      }
#pragma unroll
      for (int mt = 0; mt < 4; ++mt)
#pragma unroll
        for (int nt = 0; nt < 4; ++nt)
          acc[mt][nt] = __builtin_amdgcn_mfma_f32_16x16x32_bf16(af[mt], bf[nt], acc[mt][nt], 0, 0, 0);
    }
  }

#pragma unroll
  for (int mt = 0; mt < 4; ++mt)
#pragma unroll
    for (int nt = 0; nt < 4; ++nt)
#pragma unroll
      for (int rr = 0; rr < 4; ++rr) {
        int m = bm * 128 + wm * 64 + mt * 16 + q4 * 4 + rr;
        int n = bn * 128 + wn * 64 + nt * 16 + l15;
        float v = acc[mt][nt][rr] + bias[n];
        if (mode == 0) {
          ((ushort_t*)Cout)[(size_t)m * N + n] = f2bf(v);
        } else {
          int t = m >> 5, b = m & 31;
          ((float*)Cout)[(size_t)b * (S_LEN * DIN) + t * DIN + n] = v;
        }
      }
}

// ---------------------------------------------------------------------------
// Bidirectional LSTM recurrence — FENCE-FREE tagged MALL exchange.
// Grid = 16 blocks: d = bx&1 (0 fwd, 1 bwd), j = bx>>1 = 32-col h slice.
// comm (u64 words): per direction, 2 ping-pong bufs x 4096 words; word
// (b, colpair cp) at index b*128+cp packs {hi32 = tag, lo32 = 2 bf16 h}.
// Producer at step sc publishes tag sc+1 into buf[(sc+1)&1]; consumer at
// step sc polls buf[sc&1] for tag sc (tag 0 = memset zeros = h_{-1}).
// Tag and value share one atomic word -> no fences needed. Overwrite safety:
// tag sc+2 lands in buf[sc&1] only after its producer consumed ALL of tag
// sc+1, which was published (post-__syncthreads, i.e. post-vmcnt-drain)
// only after every WG finished reading tag sc.
// ---------------------------------------------------------------------------
__global__ __launch_bounds__(256) void lstm_layer(
    const ushort_t* __restrict__ xpf, const ushort_t* __restrict__ xpb,
    const ushort_t* __restrict__ whhf, const ushort_t* __restrict__ whhb,
    ushort_t* __restrict__ hout, u64* __restrict__ comm)
{
  const int bx = blockIdx.x;
  const int d = bx & 1, j = bx >> 1;

  const ushort_t* xp  = d ? xpb : xpf;
  const ushort_t* whh = d ? whhb : whhf;
  u64* commd = comm + (size_t)d * 8192;  // 2 bufs x 4096 u64
  const int hoff = d * 256;

  __shared__ __align__(16) ushort_t hbuf[32 * 264];  // h_{t-1}, row stride 264
  __shared__ __align__(16) float stage[32 * 132];    // gates fp32

  const int tid = threadIdx.x, lane = tid & 63, w = tid >> 6;
  const int l15 = lane & 15, q4 = lane >> 4;

  // permanent B-fragments: wave w owns gate w of this slice (32 gate rows x 2 tiles)
  short8 Bf[2][8];
#pragma unroll
  for (int tl = 0; tl < 2; ++tl) {
    int grow = w * 256 + j * 32 + tl * 16 + l15;
#pragma unroll
    for (int ks = 0; ks < 8; ++ks)
      Bf[tl][ks] = *(const short8*)(whh + (size_t)grow * 256 + ks * 32 + q4 * 8);
  }

  float cst[4] = {0.f, 0.f, 0.f, 0.f};

  ushort_t xr[2][2][4];
  auto ldxp = [&](int tt) {
#pragma unroll
    for (int mt = 0; mt < 2; ++mt)
#pragma unroll
      for (int tl = 0; tl < 2; ++tl) {
        int g = w * 256 + j * 32 + tl * 16 + l15;
#pragma unroll
        for (int rr = 0; rr < 4; ++rr) {
          int b = mt * 16 + q4 * 4 + rr;
          xr[mt][tl][rr] = xp[(size_t)tt * (BATCH * GDIM) + b * GDIM + g];
        }
      }
  };

  // consumer word assignment: thread t owns words [16t, 16t+16)
  const int cb  = tid >> 3;            // h row (batch) 0..31
  const int cw0 = (tid & 7) * 16;      // first colpair
  // producer indices
  const int pq = tid & 31;             // h col within slice
  const int pb0 = tid >> 5;            // base batch row
  const int rrlo = (tid & 1) ? 2 : 0;  // even threads store rr 0,1; odd rr 2,3

  ldxp((d == 0) ? 0 : 1023);

  for (int sc = 0; sc < 1024; ++sc) {
    const int tcur  = (d == 0) ? sc : 1023 - sc;
    const int tnext = (d == 0) ? (sc < 1023 ? sc + 1 : 1023) : (sc < 1023 ? 1022 - sc : 0);

    floatx4 acc[2][2];
#pragma unroll
    for (int mt = 0; mt < 2; ++mt)
#pragma unroll
      for (int tl = 0; tl < 2; ++tl)
#pragma unroll
        for (int rr = 0; rr < 4; ++rr) acc[mt][tl][rr] = bf2f(xr[mt][tl][rr]);

    ldxp(tnext);  // prefetch next step's xp (completes during poll)

    // ---- poll h_{t-1}: tag == sc in buf[sc&1] ----
    const u64* rbuf = commd + (size_t)(sc & 1) * 4096;
    const unsigned want = (unsigned)sc;
    u64 v[16];
#pragma unroll
    for (int k = 0; k < 16; ++k)
      v[k] = __hip_atomic_load(rbuf + cb * 128 + cw0 + k, __ATOMIC_RELAXED, __HIP_MEMORY_SCOPE_AGENT);
    for (;;) {
      bool ok = true;
#pragma unroll
      for (int k = 0; k < 16; ++k) ok = ok && ((unsigned)(v[k] >> 32) == want);
      if (ok) break;
#pragma unroll
      for (int k = 0; k < 16; ++k)
        if ((unsigned)(v[k] >> 32) != want)
          v[k] = __hip_atomic_load(rbuf + cb * 128 + cw0 + k, __ATOMIC_RELAXED, __HIP_MEMORY_SCOPE_AGENT);
    }
    // unpack to LDS
    {
      uint_t* hrow = (uint_t*)hbuf + cb * 132 + cw0;
#pragma unroll
      for (int k = 0; k < 16; ++k) hrow[k] = (uint_t)v[k];
    }
    __syncthreads();

    // ---- gates = xp + h_{t-1} @ whh^T via MFMA ----
#pragma unroll
    for (int ks = 0; ks < 8; ++ks) {
      short8 a0 = *(const short8*)(hbuf + l15 * 264 + ks * 32 + q4 * 8);
      short8 a1 = *(const short8*)(hbuf + (16 + l15) * 264 + ks * 32 + q4 * 8);
      acc[0][0] = __builtin_amdgcn_mfma_f32_16x16x32_bf16(a0, Bf[0][ks], acc[0][0], 0, 0, 0);
      acc[0][1] = __builtin_amdgcn_mfma_f32_16x16x32_bf16(a0, Bf[1][ks], acc[0][1], 0, 0, 0);
      acc[1][0] = __builtin_amdgcn_mfma_f32_16x16x32_bf16(a1, Bf[0][ks], acc[1][0], 0, 0, 0);
      acc[1][1] = __builtin_amdgcn_mfma_f32_16x16x32_bf16(a1, Bf[1][ks], acc[1][1], 0, 0, 0);
    }

#pragma unroll
    for (int mt = 0; mt < 2; ++mt)
#pragma unroll
      for (int tl = 0; tl < 2; ++tl)
#pragma unroll
        for (int rr = 0; rr < 4; ++rr)
          stage[(mt * 16 + q4 * 4 + rr) * 132 + w * 32 + tl * 16 + l15] = acc[mt][tl][rr];
    __syncthreads();

    // ---- elementwise LSTM cell (thread handles batches pb0+8rr, col pq) ----
    float hv[4];
#pragma unroll
    for (int rr = 0; rr < 4; ++rr) {
      int b = pb0 + 8 * rr;
      float gi = stage[b * 132 + pq];
      float gf = stage[b * 132 + 32 + pq];
      float gg = stage[b * 132 + 64 + pq];
      float go = stage[b * 132 + 96 + pq];
      float c = sigf(gf) * cst[rr] + sigf(gi) * tanh_f(gg);
      cst[rr] = c;
      hv[rr] = sigf(go) * tanh_f(c);
    }

    // ---- exchange partner values with UNIFORM shuffles (R2 bugfix:
    // __shfl with a lane-dependent register index made even lanes
    // receive the partner's hv[2+s] instead of hv[s]) ----
    float oth[4];
#pragma unroll
    for (int rr = 0; rr < 4; ++rr) oth[rr] = __shfl(hv[rr], lane ^ 1);

    // ---- publish h_t (tag sc+1) into buf[(sc+1)&1] + hout ----
    u64* wbuf = commd + (size_t)((sc + 1) & 1) * 4096;
    const u64 tagw = ((u64)(unsigned)(sc + 1)) << 32;
#pragma unroll
    for (int s = 0; s < 2; ++s) {
      int rr = rrlo + s;
      ushort_t me = f2bf(hv[rr]), ot = f2bf(oth[rr]);
      uint_t lo = (tid & 1) ? (((uint_t)me << 16) | (uint_t)ot) : (((uint_t)ot << 16) | (uint_t)me);
      int b = pb0 + 8 * rr;
      int cp = j * 16 + (pq >> 1);
      __hip_atomic_store(wbuf + b * 128 + cp, tagw | (u64)lo, __ATOMIC_RELAXED, __HIP_MEMORY_SCOPE_AGENT);
      ((uint_t*)hout)[((size_t)tcur * (BATCH * 512) + b * 512 + hoff + j * 32 + (pq & ~1)) >> 1] = lo;
    }
  }
}

// ---------------------------------------------------------------------------
// Attention scores -> e = exp(s - max_t s), per batch b.
// ---------------------------------------------------------------------------
__global__ __launch_bounds__(256) void attn_scores(
    const ushort_t* __restrict__ h1, const float* __restrict__ attn_w,
    const float* __restrict__ attn_b, float* __restrict__ e_out)
{
  const int b = blockIdx.x;
  __shared__ float sbuf[1024];
  __shared__ float red[4];
  const int tid = threadIdx.x, lane = tid & 63, w = tid >> 6;

  float wreg[8];
#pragma unroll
  for (int i = 0; i < 8; ++i) wreg[i] = attn_w[lane * 8 + i];

  for (int t = w; t < 1024; t += 4) {
    short8 hv = *(const short8*)(h1 + (size_t)t * (BATCH * 512) + b * 512 + lane * 8);
    float dot = 0.f;
#pragma unroll
    for (int i = 0; i < 8; ++i) dot += bf2fs(hv[i]) * wreg[i];
#pragma unroll
    for (int off = 32; off; off >>= 1) dot += __shfl_xor(dot, off);
    if (lane == 0) sbuf[t] = dot + attn_b[0];
  }
  __syncthreads();
  float m = -1e30f;
  for (int t = tid; t < 1024; t += 256) m = fmaxf(m, sbuf[t]);
#pragma unroll
  for (int off = 32; off; off >>= 1) m = fmaxf(m, __shfl_xor(m, off));
  if (lane == 0) red[w] = m;
  __syncthreads();
  float mm = fmaxf(fmaxf(red[0], red[1]), fmaxf(red[2], red[3]));
  for (int t = tid; t < 1024; t += 256) e_out[b * 1024 + t] = __expf(sbuf[t] - mm);
}

// ---------------------------------------------------------------------------
// Cumulative context: ctx[t][b][c] = (sum_{u<=t} e_u h_u[c]) / (sum e_u), bf16.
// ---------------------------------------------------------------------------
__global__ __launch_bounds__(256) void attn_ctx(
    const ushort_t* __restrict__ h1, const float* __restrict__ e_in, ushort_t* __restrict__ ctx)
{
  const int b = blockIdx.x >> 1, half = blockIdx.x & 1;
  const int c = half * 256 + threadIdx.x;
  float num = 0.f, den = 0.f;
  const ushort_t* hp = h1 + b * 512 + c;
  ushort_t* cp = ctx + b * 512 + c;
  const float* ep = e_in + b * 1024;
#pragma unroll 4
  for (int t = 0; t < 1024; ++t) {
    float ev = ep[t];
    float hv = bf2f(hp[(size_t)t * (BATCH * 512)]);
    num += ev * hv;
    den += ev;
    cp[(size_t)t * (BATCH * 512)] = f2bf(num / den);
  }
}

// ---------------------------------------------------------------------------
// casts
// ---------------------------------------------------------------------------
__global__ void castw(const float* __restrict__ in, ushort_t* __restrict__ out, int n) {
  int i = blockIdx.x * 256 + threadIdx.x;
  if (i < n) out[i] = f2bf(in[i]);
}
__global__ void castx(const float* __restrict__ x, ushort_t* __restrict__ xt) {
  int i = blockIdx.x * 256 + threadIdx.x;  // over 32768*128
  int dcol = i & 127;
  int m = i >> 7;
  int b = m & 31, s = m >> 5;
  xt[i] = f2bf(x[(size_t)b * (S_LEN * DIN) + s * DIN + dcol]);
}

extern "C" void kernel_launch(void* const* d_in, const int* in_sizes, int n_in,
                              void* d_out, int out_size, void* d_ws, size_t ws_size,
                              hipStream_t stream)
{
  const float* x     = (const float*)d_in[0];
  const float* wih0f = (const float*)d_in[1];
  const float* whh0f = (const float*)d_in[2];
  const float* b0f   = (const float*)d_in[3];
  const float* wih0b = (const float*)d_in[4];
  const float* whh0b = (const float*)d_in[5];
  const float* b0b   = (const float*)d_in[6];
  const float* wih1f = (const float*)d_in[7];
  const float* whh1f = (const float*)d_in[8];
  const float* b1f   = (const float*)d_in[9];
  const float* wih1b = (const float*)d_in[10];
  const float* whh1b = (const float*)d_in[11];
  const float* b1b   = (const float*)d_in[12];
  const float* attw  = (const float*)d_in[13];
  const float* attb  = (const float*)d_in[14];
  const float* headw = (const float*)d_in[15];
  const float* headb = (const float*)d_in[16];
  float* out = (float*)d_out;

  char* p = (char*)d_ws;
  auto alloc = [&](size_t bytes) {
    char* r = p;
    p += (bytes + 255) & ~(size_t)255;
    return r;
  };
  u64* comm       = (u64*)alloc(2 * 8192 * 8);  // 2 dir x 2 bufs x 4096 u64
  ushort_t* xt    = (ushort_t*)alloc((size_t)32768 * 128 * 2);
  ushort_t* cwih0f = (ushort_t*)alloc(131072 * 2);
  ushort_t* cwih0b = (ushort_t*)alloc(131072 * 2);
  ushort_t* cwhh0f = (ushort_t*)alloc(262144 * 2);
  ushort_t* cwhh0b = (ushort_t*)alloc(262144 * 2);
  ushort_t* cwih1f = (ushort_t*)alloc(524288 * 2);
  ushort_t* cwih1b = (ushort_t*)alloc(524288 * 2);
  ushort_t* cwhh1f = (ushort_t*)alloc(262144 * 2);
  ushort_t* cwhh1b = (ushort_t*)alloc(262144 * 2);
  ushort_t* cwhead = (ushort_t*)alloc(65536 * 2);
  ushort_t* xpA = (ushort_t*)alloc((size_t)32768 * 1024 * 2);
  ushort_t* xpB = (ushort_t*)alloc((size_t)32768 * 1024 * 2);
  ushort_t* h0  = (ushort_t*)alloc((size_t)32768 * 512 * 2);
  ushort_t* h1  = (ushort_t*)alloc((size_t)32768 * 512 * 2);
  float* ebuf   = (float*)alloc(32 * 1024 * 4);
  ushort_t* ctx = xpA;  // reuse (xp dead by then)

  (void)in_sizes; (void)n_in; (void)out_size; (void)ws_size;

  // tag 0 + h_{-1}=0 for layer 0
  (void)hipMemsetAsync(comm, 0, 2 * 8192 * 8, stream);

  castw<<<512, 256, 0, stream>>>(wih0f, cwih0f, 131072);
  castw<<<512, 256, 0, stream>>>(wih0b, cwih0b, 131072);
  castw<<<1024, 256, 0, stream>>>(whh0f, cwhh0f, 262144);
  castw<<<1024, 256, 0, stream>>>(whh0b, cwhh0b, 262144);
  castw<<<2048, 256, 0, stream>>>(wih1f, cwih1f, 524288);
  castw<<<2048, 256, 0, stream>>>(wih1b, cwih1b, 524288);
  castw<<<1024, 256, 0, stream>>>(whh1f, cwhh1f, 262144);
  castw<<<1024, 256, 0, stream>>>(whh1b, cwhh1b, 262144);
  castw<<<256, 256, 0, stream>>>(headw, cwhead, 65536);
  castx<<<16384, 256, 0, stream>>>(x, xt);

  // layer 0
  gemm_bf16<<<dim3(8, 256), 256, 0, stream>>>(xt, cwih0f, b0f, xpA, 32768, 1024, 128, 0);
  gemm_bf16<<<dim3(8, 256), 256, 0, stream>>>(xt, cwih0b, b0b, xpB, 32768, 1024, 128, 0);
  lstm_layer<<<16, 256, 0, stream>>>(xpA, xpB, cwhh0f, cwhh0b, h0, comm);

  // reset tags for layer 1
  (void)hipMemsetAsync(comm, 0, 2 * 8192 * 8, stream);

  // layer 1
  gemm_bf16<<<dim3(8, 256), 256, 0, stream>>>(h0, cwih1f, b1f, xpA, 32768, 1024, 512, 0);
  gemm_bf16<<<dim3(8, 256), 256, 0, stream>>>(h0, cwih1b, b1b, xpB, 32768, 1024, 512, 0);
  lstm_layer<<<16, 256, 0, stream>>>(xpA, xpB, cwhh1f, cwhh1b, h1, comm);

  // attention + head
  attn_scores<<<32, 256, 0, stream>>>(h1, attw, attb, ebuf);
  attn_ctx<<<64, 256, 0, stream>>>(h1, ebuf, ctx);
  gemm_bf16<<<dim3(1, 256), 256, 0, stream>>>(ctx, cwhead, headb, out, 32768, 128, 512, 1);
}

// Round 7
// 7734.868 us; speedup vs baseline: 1.3955x; 1.3179x over previous
//
#include <hip/hip_runtime.h>

typedef unsigned short ushort_t;
typedef unsigned int uint_t;
typedef unsigned long long u64;
typedef __attribute__((ext_vector_type(8))) short short8;
typedef __attribute__((ext_vector_type(4))) float floatx4;

#define S_LEN 1024
#define BATCH 32
#define HDIM  256
#define GDIM  1024  /* 4H */
#define DIN   128
#define SALT  0x00C0FFEE00000000ULL

__device__ __forceinline__ float bf2f(ushort_t u) { return __uint_as_float(((unsigned)u) << 16); }
__device__ __forceinline__ float bf2fs(short s)   { return __uint_as_float(((unsigned)(unsigned short)s) << 16); }
__device__ __forceinline__ ushort_t f2bf(float f) {
  unsigned u = __float_as_uint(f);
  unsigned r = (u + 0x7fffu + ((u >> 16) & 1u)) >> 16;
  return (ushort_t)r;
}
__device__ __forceinline__ float sigf(float x) { return 1.f / (1.f + __expf(-x)); }
__device__ __forceinline__ float tanh_f(float x) {
  float ax = fabsf(x);
  float e = __expf(2.f * ax);
  float r = 1.f - 2.f / (e + 1.f);
  return x < 0.f ? -r : r;
}

__device__ __forceinline__ void load_lds16(const void* g, void* l) {
  __builtin_amdgcn_global_load_lds((const __attribute__((address_space(1))) unsigned int*)g,
                                   (__attribute__((address_space(3))) unsigned int*)l, 16, 0, 0);
}
__device__ __forceinline__ void vm0() { asm volatile("s_waitcnt vmcnt(0)" ::: "memory"); }

// ---------------------------------------------------------------------------
// Generic bf16 MFMA GEMM: C[m][n] = sum_k A[m][k]*B[n][k] + bias[n]
// mode 0: bf16 at C[m*N+n]          (h layout [t][b][n], m = t*32+b)
// mode 1: fp32 at out[b][t][n]      (head output)
// mode 2: bf16 at C[t][n][b]        (xp transposed for vectorized recurrence)
// ---------------------------------------------------------------------------
__global__ __launch_bounds__(256) void gemm_bf16(
    const ushort_t* __restrict__ A, const ushort_t* __restrict__ Bw,
    const float* __restrict__ bias, void* __restrict__ Cout,
    int M, int N, int K, int mode)
{
  __shared__ __align__(16) ushort_t As[128 * 64];
  __shared__ __align__(16) ushort_t Bs[128 * 64];
  const int tid = threadIdx.x;
  const int lane = tid & 63, wid = tid >> 6;
  const int wm = wid >> 1, wn = wid & 1;
  const int bm = blockIdx.y, bn = blockIdx.x;
  const int l15 = lane & 15, q4 = lane >> 4;

  const int r  = tid >> 3;
  const int c8 = tid & 7;
  const int g8 = c8 ^ (r & 7);

  floatx4 zero4 = {0.f, 0.f, 0.f, 0.f};
  floatx4 acc[4][4];
#pragma unroll
  for (int mt = 0; mt < 4; ++mt)
#pragma unroll
    for (int nt = 0; nt < 4; ++nt) acc[mt][nt] = zero4;

  for (int k0 = 0; k0 < K; k0 += 64) {
    __syncthreads();
#pragma unroll
    for (int p = 0; p < 4; ++p) {
      int row = p * 32 + r;
      load_lds16(A + (size_t)(bm * 128 + row) * K + k0 + g8 * 8, (void*)(As + p * 2048 + wid * 512));
      load_lds16(Bw + (size_t)(bn * 128 + row) * K + k0 + g8 * 8, (void*)(Bs + p * 2048 + wid * 512));
    }
    __syncthreads();
#pragma unroll
    for (int ks = 0; ks < 2; ++ks) {
      const int kk = ks * 4 + q4;
      short8 af[4], bf[4];
#pragma unroll
      for (int mt = 0; mt < 4; ++mt) {
        int row = wm * 64 + mt * 16 + l15;
        af[mt] = *(const short8*)(As + row * 64 + ((kk ^ (row & 7)) << 3));
      }
#pragma unroll
      for (int nt = 0; nt < 4; ++nt) {
        int row = wn * 64 + nt * 16 + l15;
        bf[nt] = *(const short8*)(Bs + row * 64 + ((kk ^ (row & 7)) << 3));
      }
#pragma unroll
      for (int mt = 0; mt < 4; ++mt)
#pragma unroll
        for (int nt = 0; nt < 4; ++nt)
          acc[mt][nt] = __builtin_amdgcn_mfma_f32_16x16x32_bf16(af[mt], bf[nt], acc[mt][nt], 0, 0, 0);
    }
  }

#pragma unroll
  for (int mt = 0; mt < 4; ++mt)
#pragma unroll
    for (int nt = 0; nt < 4; ++nt)
#pragma unroll
      for (int rr = 0; rr < 4; ++rr) {
        int m = bm * 128 + wm * 64 + mt * 16 + q4 * 4 + rr;
        int n = bn * 128 + wn * 64 + nt * 16 + l15;
        float v = acc[mt][nt][rr] + bias[n];
        if (mode == 0) {
          ((ushort_t*)Cout)[(size_t)m * N + n] = f2bf(v);
        } else if (mode == 1) {
          int t = m >> 5, b = m & 31;
          ((float*)Cout)[(size_t)b * (S_LEN * DIN) + t * DIN + n] = v;
        } else {
          int t = m >> 5, b = m & 31;
          ((ushort_t*)Cout)[(size_t)t * (N * 32) + n * 32 + b] = f2bf(v);
        }
      }
}

// ---------------------------------------------------------------------------
// Bidirectional LSTM recurrence — MALL epoch-gated bulk exchange.
// Grid = 16 WGs: dir = bx&1, j = bx>>1 (32-col h slice). Proven-coherent
// device-scope (agent) atomics only; no cache-flag games (R6 falsified sc0).
// Per step: producer stores its 256 data u64s (1/thread, 4 bf16 cols each),
// vmcnt(0)+barrier, thread0 stores salted epoch (SALT|step) for (parity,j).
// Consumers: wave0 polls the 8 epoch words (lane-parallel + ballot), then all
// threads bulk-read 2048 data words once (no retry) -> LDS -> MFMA.
// Overwrite-safety: epoch sc+2 for buf[p] is stored only after its WG read
// all epochs sc+1, each of which is stored only after that WG's step-sc data
// reads from buf[p] completed (vmcnt-drained before its barrier). Graph-replay
// safe: epochs zeroed per launch, SALT != 0 / 0xAA poison; data gated.
// xp consumed from transposed [t][g][b] layout -> 4x u64 loads per thread.
// ---------------------------------------------------------------------------
__global__ __launch_bounds__(256) void lstm_layer(
    const ushort_t* __restrict__ xpf, const ushort_t* __restrict__ xpb,
    const ushort_t* __restrict__ whhf, const ushort_t* __restrict__ whhb,
    ushort_t* __restrict__ hout, u64* __restrict__ comm, u64* __restrict__ epochs)
{
  const int bx = blockIdx.x;
  const int dir = bx & 1, j = bx >> 1;

  const ushort_t* xp  = dir ? xpb : xpf;
  const ushort_t* whh = dir ? whhb : whhf;
  u64* commd = comm + (size_t)dir * 4096;  // 2 parities x 2048 u64
  const int hoff = dir * 256;

  __shared__ __align__(16) ushort_t hbuf[32 * 264];  // h_{t-1} bf16, stride 264
  __shared__ __align__(16) float stage[32 * 132];    // gates fp32

  const int tid = threadIdx.x, lane = tid & 63, w = tid >> 6;
  const int l15 = lane & 15, q4 = lane >> 4;

  // permanent B-fragments: wave w owns gate w of slice j (32 gate rows, 2 tiles)
  short8 Bf[2][8];
#pragma unroll
  for (int tl = 0; tl < 2; ++tl) {
    int grow = w * 256 + j * 32 + tl * 16 + l15;
#pragma unroll
    for (int ks = 0; ks < 8; ++ks)
      Bf[tl][ks] = *(const short8*)(whh + (size_t)grow * 256 + ks * 32 + q4 * 8);
  }

  // zero hbuf: h_{-1} = 0 (sc==0 skips the consume phase)
  for (int i = tid; i < 32 * 132; i += 256) ((uint_t*)hbuf)[i] = 0u;

  float cst[4] = {0.f, 0.f, 0.f, 0.f};

  // xp prefetch: [t][g][b] layout, one u64 = 4 consecutive batches
  u64 xr64[2][2];
  auto ldxp = [&](int tt) {
#pragma unroll
    for (int mt = 0; mt < 2; ++mt)
#pragma unroll
      for (int tl = 0; tl < 2; ++tl) {
        int g = w * 256 + j * 32 + tl * 16 + l15;
        xr64[mt][tl] = *(const u64*)(xp + (size_t)tt * (GDIM * BATCH) + (size_t)g * 32 + mt * 16 + q4 * 4);
      }
  };

  const int cb  = tid >> 3;      // consumer batch row
  const int cg0 = tid & 7;       // consumer col-group octet
  const int bb  = tid >> 3;      // producer batch
  const int c4  = (tid & 7) * 4; // producer first col (4 consecutive)

  ldxp((dir == 0) ? 0 : 1023);
  __syncthreads();

  for (int sc = 0; sc < 1024; ++sc) {
    const int tcur  = (dir == 0) ? sc : 1023 - sc;
    const int tnext = (dir == 0) ? (sc < 1023 ? sc + 1 : 1023) : (sc < 1023 ? 1022 - sc : 0);

    floatx4 acc[2][2];
#pragma unroll
    for (int mt = 0; mt < 2; ++mt)
#pragma unroll
      for (int tl = 0; tl < 2; ++tl) {
        u64 v = xr64[mt][tl];
#pragma unroll
        for (int rr = 0; rr < 4; ++rr)
          acc[mt][tl][rr] = bf2f((ushort_t)(v >> (16 * rr)));
      }

    ldxp(tnext);  // prefetch next step's xp (latency hidden under poll+MFMA)

    // ---- consume h_{t-1} ----
    if (sc > 0) {
      if (w == 0) {  // wave 0: lane-parallel epoch poll
        const u64 want = SALT | (u64)(unsigned)sc;
        const u64* ea = epochs + ((size_t)(dir * 2 + (sc & 1)) * 8 + (lane & 7)) * 16;
        for (;;) {
          u64 v = __hip_atomic_load(ea, __ATOMIC_RELAXED, __HIP_MEMORY_SCOPE_AGENT);
          if (__ballot(v == want) == ~0ULL) break;
        }
      }
      __syncthreads();
      const u64* rbuf = commd + (size_t)(sc & 1) * 2048 + (size_t)cb * 64 + cg0 * 8;
      u64 tmp[8];
#pragma unroll
      for (int k = 0; k < 8; ++k)
        tmp[k] = __hip_atomic_load(rbuf + k, __ATOMIC_RELAXED, __HIP_MEMORY_SCOPE_AGENT);
#pragma unroll
      for (int k = 0; k < 8; ++k)
        *(u64*)(hbuf + cb * 264 + cg0 * 32 + k * 4) = tmp[k];
    }
    __syncthreads();

    // ---- gates = xp + h_{t-1} @ whh^T via MFMA ----
#pragma unroll
    for (int ks = 0; ks < 8; ++ks) {
      short8 a0 = *(const short8*)(hbuf + l15 * 264 + ks * 32 + q4 * 8);
      short8 a1 = *(const short8*)(hbuf + (16 + l15) * 264 + ks * 32 + q4 * 8);
      acc[0][0] = __builtin_amdgcn_mfma_f32_16x16x32_bf16(a0, Bf[0][ks], acc[0][0], 0, 0, 0);
      acc[0][1] = __builtin_amdgcn_mfma_f32_16x16x32_bf16(a0, Bf[1][ks], acc[0][1], 0, 0, 0);
      acc[1][0] = __builtin_amdgcn_mfma_f32_16x16x32_bf16(a1, Bf[0][ks], acc[1][0], 0, 0, 0);
      acc[1][1] = __builtin_amdgcn_mfma_f32_16x16x32_bf16(a1, Bf[1][ks], acc[1][1], 0, 0, 0);
    }

#pragma unroll
    for (int mt = 0; mt < 2; ++mt)
#pragma unroll
      for (int tl = 0; tl < 2; ++tl)
#pragma unroll
        for (int rr = 0; rr < 4; ++rr)
          stage[(mt * 16 + q4 * 4 + rr) * 132 + w * 32 + tl * 16 + l15] = acc[mt][tl][rr];
    __syncthreads();

    // ---- elementwise LSTM cell: thread = (batch bb, cols c4..c4+3) ----
    float hv4[4];
#pragma unroll
    for (int i = 0; i < 4; ++i) {
      float gi = stage[bb * 132 +       c4 + i];
      float gf = stage[bb * 132 + 32  + c4 + i];
      float gg = stage[bb * 132 + 64  + c4 + i];
      float go = stage[bb * 132 + 96  + c4 + i];
      float c = sigf(gf) * cst[i] + sigf(gi) * tanh_f(gg);
      cst[i] = c;
      hv4[i] = sigf(go) * tanh_f(c);
    }
    u64 pv = (u64)f2bf(hv4[0]) | ((u64)f2bf(hv4[1]) << 16) |
             ((u64)f2bf(hv4[2]) << 32) | ((u64)f2bf(hv4[3]) << 48);

    // ---- publish: data word -> vmcnt drain -> barrier -> epoch ----
    __hip_atomic_store(commd + (size_t)((sc + 1) & 1) * 2048 + (size_t)bb * 64 + j * 8 + (tid & 7),
                       pv, __ATOMIC_RELAXED, __HIP_MEMORY_SCOPE_AGENT);
    *(u64*)(hout + (size_t)tcur * (BATCH * 512) + bb * 512 + hoff + j * 32 + c4) = pv;
    vm0();
    __syncthreads();
    if (tid == 0)
      __hip_atomic_store(epochs + ((size_t)(dir * 2 + ((sc + 1) & 1)) * 8 + j) * 16,
                         SALT | (u64)(unsigned)(sc + 1), __ATOMIC_RELAXED, __HIP_MEMORY_SCOPE_AGENT);
  }
}

// ---------------------------------------------------------------------------
// Attention scores -> e = exp(s - max_t s), per batch b.
// ---------------------------------------------------------------------------
__global__ __launch_bounds__(256) void attn_scores(
    const ushort_t* __restrict__ h1, const float* __restrict__ attn_w,
    const float* __restrict__ attn_b, float* __restrict__ e_out)
{
  const int b = blockIdx.x;
  __shared__ float sbuf[1024];
  __shared__ float red[4];
  const int tid = threadIdx.x, lane = tid & 63, w = tid >> 6;

  float wreg[8];
#pragma unroll
  for (int i = 0; i < 8; ++i) wreg[i] = attn_w[lane * 8 + i];

  for (int t = w; t < 1024; t += 4) {
    short8 hv = *(const short8*)(h1 + (size_t)t * (BATCH * 512) + b * 512 + lane * 8);
    float dot = 0.f;
#pragma unroll
    for (int i = 0; i < 8; ++i) dot += bf2fs(hv[i]) * wreg[i];
#pragma unroll
    for (int off = 32; off; off >>= 1) dot += __shfl_xor(dot, off);
    if (lane == 0) sbuf[t] = dot + attn_b[0];
  }
  __syncthreads();
  float m = -1e30f;
  for (int t = tid; t < 1024; t += 256) m = fmaxf(m, sbuf[t]);
#pragma unroll
  for (int off = 32; off; off >>= 1) m = fmaxf(m, __shfl_xor(m, off));
  if (lane == 0) red[w] = m;
  __syncthreads();
  float mm = fmaxf(fmaxf(red[0], red[1]), fmaxf(red[2], red[3]));
  for (int t = tid; t < 1024; t += 256) e_out[b * 1024 + t] = __expf(sbuf[t] - mm);
}

// ---------------------------------------------------------------------------
// Cumulative context: ctx[t][b][c] = (sum_{u<=t} e_u h_u[c]) / (sum e_u), bf16.
// ---------------------------------------------------------------------------
__global__ __launch_bounds__(256) void attn_ctx(
    const ushort_t* __restrict__ h1, const float* __restrict__ e_in, ushort_t* __restrict__ ctx)
{
  const int b = blockIdx.x >> 1, half = blockIdx.x & 1;
  const int c = half * 256 + threadIdx.x;
  float num = 0.f, den = 0.f;
  const ushort_t* hp = h1 + b * 512 + c;
  ushort_t* cp = ctx + b * 512 + c;
  const float* ep = e_in + b * 1024;
#pragma unroll 4
  for (int t = 0; t < 1024; ++t) {
    float ev = ep[t];
    float hv = bf2f(hp[(size_t)t * (BATCH * 512)]);
    num += ev * hv;
    den += ev;
    cp[(size_t)t * (BATCH * 512)] = f2bf(num / den);
  }
}

// ---------------------------------------------------------------------------
// casts
// ---------------------------------------------------------------------------
__global__ void castw(const float* __restrict__ in, ushort_t* __restrict__ out, int n) {
  int i = blockIdx.x * 256 + threadIdx.x;
  if (i < n) out[i] = f2bf(in[i]);
}
__global__ void castx(const float* __restrict__ x, ushort_t* __restrict__ xt) {
  int i = blockIdx.x * 256 + threadIdx.x;  // over 32768*128
  int dcol = i & 127;
  int m = i >> 7;
  int b = m & 31, s = m >> 5;
  xt[i] = f2bf(x[(size_t)b * (S_LEN * DIN) + s * DIN + dcol]);
}

extern "C" void kernel_launch(void* const* d_in, const int* in_sizes, int n_in,
                              void* d_out, int out_size, void* d_ws, size_t ws_size,
                              hipStream_t stream)
{
  const float* x     = (const float*)d_in[0];
  const float* wih0f = (const float*)d_in[1];
  const float* whh0f = (const float*)d_in[2];
  const float* b0f   = (const float*)d_in[3];
  const float* wih0b = (const float*)d_in[4];
  const float* whh0b = (const float*)d_in[5];
  const float* b0b   = (const float*)d_in[6];
  const float* wih1f = (const float*)d_in[7];
  const float* whh1f = (const float*)d_in[8];
  const float* b1f   = (const float*)d_in[9];
  const float* wih1b = (const float*)d_in[10];
  const float* whh1b = (const float*)d_in[11];
  const float* b1b   = (const float*)d_in[12];
  const float* attw  = (const float*)d_in[13];
  const float* attb  = (const float*)d_in[14];
  const float* headw = (const float*)d_in[15];
  const float* headb = (const float*)d_in[16];
  float* out = (float*)d_out;

  char* p = (char*)d_ws;
  auto alloc = [&](size_t bytes) {
    char* r = p;
    p += (bytes + 511) & ~(size_t)511;
    return r;
  };
  u64* ep0        = (u64*)alloc(512 * 8);   // layer-0 epochs (2 dir x 2 par x 8 j x 16 u64)
  u64* ep1        = (u64*)alloc(512 * 8);   // layer-1 epochs
  u64* comm0      = (u64*)alloc(8192 * 8);  // layer-0 data: 2 dir x 2 par x 2048 u64
  u64* comm1      = (u64*)alloc(8192 * 8);
  ushort_t* xt    = (ushort_t*)alloc((size_t)32768 * 128 * 2);
  ushort_t* cwih0f = (ushort_t*)alloc(131072 * 2);
  ushort_t* cwih0b = (ushort_t*)alloc(131072 * 2);
  ushort_t* cwhh0f = (ushort_t*)alloc(262144 * 2);
  ushort_t* cwhh0b = (ushort_t*)alloc(262144 * 2);
  ushort_t* cwih1f = (ushort_t*)alloc(524288 * 2);
  ushort_t* cwih1b = (ushort_t*)alloc(524288 * 2);
  ushort_t* cwhh1f = (ushort_t*)alloc(262144 * 2);
  ushort_t* cwhh1b = (ushort_t*)alloc(262144 * 2);
  ushort_t* cwhead = (ushort_t*)alloc(65536 * 2);
  ushort_t* xpA = (ushort_t*)alloc((size_t)32768 * 1024 * 2);
  ushort_t* xpB = (ushort_t*)alloc((size_t)32768 * 1024 * 2);
  ushort_t* h0  = (ushort_t*)alloc((size_t)32768 * 512 * 2);
  ushort_t* h1  = (ushort_t*)alloc((size_t)32768 * 512 * 2);
  float* ebuf   = (float*)alloc(32 * 1024 * 4);
  ushort_t* ctx = xpA;  // reuse (xp dead by then)

  (void)in_sizes; (void)n_in; (void)out_size; (void)ws_size;

  // zero both layers' epoch arrays (data words are epoch-gated; no init needed)
  (void)hipMemsetAsync(ep0, 0, 2 * 512 * 8, stream);

  castw<<<512, 256, 0, stream>>>(wih0f, cwih0f, 131072);
  castw<<<512, 256, 0, stream>>>(wih0b, cwih0b, 131072);
  castw<<<1024, 256, 0, stream>>>(whh0f, cwhh0f, 262144);
  castw<<<1024, 256, 0, stream>>>(whh0b, cwhh0b, 262144);
  castw<<<2048, 256, 0, stream>>>(wih1f, cwih1f, 524288);
  castw<<<2048, 256, 0, stream>>>(wih1b, cwih1b, 524288);
  castw<<<1024, 256, 0, stream>>>(whh1f, cwhh1f, 262144);
  castw<<<1024, 256, 0, stream>>>(whh1b, cwhh1b, 262144);
  castw<<<256, 256, 0, stream>>>(headw, cwhead, 65536);
  castx<<<16384, 256, 0, stream>>>(x, xt);

  // layer 0: xp in transposed [t][g][b] layout (mode 2)
  gemm_bf16<<<dim3(8, 256), 256, 0, stream>>>(xt, cwih0f, b0f, xpA, 32768, 1024, 128, 2);
  gemm_bf16<<<dim3(8, 256), 256, 0, stream>>>(xt, cwih0b, b0b, xpB, 32768, 1024, 128, 2);
  lstm_layer<<<16, 256, 0, stream>>>(xpA, xpB, cwhh0f, cwhh0b, h0, comm0, ep0);

  // layer 1
  gemm_bf16<<<dim3(8, 256), 256, 0, stream>>>(h0, cwih1f, b1f, xpA, 32768, 1024, 512, 2);
  gemm_bf16<<<dim3(8, 256), 256, 0, stream>>>(h0, cwih1b, b1b, xpB, 32768, 1024, 512, 2);
  lstm_layer<<<16, 256, 0, stream>>>(xpA, xpB, cwhh1f, cwhh1b, h1, comm1, ep1);

  // attention + head
  attn_scores<<<32, 256, 0, stream>>>(h1, attw, attb, ebuf);
  attn_ctx<<<64, 256, 0, stream>>>(h1, ebuf, ctx);
  gemm_bf16<<<dim3(1, 256), 256, 0, stream>>>(ctx, cwhead, headb, out, 32768, 128, 512, 1);
}